// Round 3
// baseline (218.850 us; speedup 1.0000x reference)
//
#include <hip/hip_runtime.h>
#include <hip/hip_bf16.h>

#define T_TOK   2048
#define NEXP    8
#define HDIM    1024
#define IDIM    768
#define TOPK    2
#define NASSIGN (T_TOK*TOPK)
#define MT      64
#define MAX_TILES 72
#define SLOT_PAD 4224

typedef unsigned short u16;
typedef unsigned int   u32;

typedef __bf16 bf16x8 __attribute__((ext_vector_type(8)));
typedef float  f32x4  __attribute__((ext_vector_type(4)));

struct Meta {
  int n_tiles;
  int _pad[15];
  int tile_e[80];
  int tile_m[80];
  int tile_n[80];   // valid rows in tile
};

__device__ __forceinline__ u16 f2bf(float f) {
  u32 x = __float_as_uint(f);
  return (u16)((x + 0x7fffu + ((x >> 16) & 1u)) >> 16);   // RNE, inputs are finite
}

__device__ __forceinline__ int4 pack8(const float* __restrict__ p) {
  float4 a = *(const float4*)p;
  float4 b = *(const float4*)(p + 4);
  union { u16 u[8]; int4 v; } r;
  r.u[0] = f2bf(a.x); r.u[1] = f2bf(a.y); r.u[2] = f2bf(a.z); r.u[3] = f2bf(a.w);
  r.u[4] = f2bf(b.x); r.u[5] = f2bf(b.y); r.u[6] = f2bf(b.z); r.u[7] = f2bf(b.w);
  return r.v;
}

__device__ __forceinline__ bf16x8 asbf(int4 v) {
  return __builtin_bit_cast(bf16x8, v);
}

// ---------------- routing: group assignments by expert ----------------
__global__ void route_k(const int* __restrict__ topk, const float* __restrict__ tw,
                        Meta* __restrict__ meta, int* __restrict__ slot_token,
                        float* __restrict__ slot_w) {
  __shared__ int s_cnt[NEXP], s_off[NEXP], s_cur[NEXP];
  int tid = threadIdx.x;
  if (tid < NEXP) { s_cnt[tid] = 0; s_cur[tid] = 0; }
  __syncthreads();
  for (int i = tid; i < NASSIGN; i += blockDim.x)
    atomicAdd(&s_cnt[topk[i]], 1);
  __syncthreads();
  if (tid == 0) {
    int acc = 0, nt = 0;
    for (int e = 0; e < NEXP; ++e) {
      s_off[e] = acc;
      int c = s_cnt[e];
      for (int mb = 0; mb < c; mb += MT) {
        meta->tile_e[nt] = e;
        meta->tile_m[nt] = acc + mb;
        meta->tile_n[nt] = (c - mb) < MT ? (c - mb) : MT;
        ++nt;
      }
      acc += c;
    }
    meta->n_tiles = nt;
  }
  __syncthreads();
  for (int i = tid; i < NASSIGN; i += blockDim.x) {
    int e = topk[i];
    int p = s_off[e] + atomicAdd(&s_cur[e], 1);
    slot_token[p] = i / TOPK;
    slot_w[p]     = tw[i];
  }
}

// ---------------- fp32 -> bf16, 4 elems/thread (hidden states) ----------------
__global__ void cvt_k(const float* __restrict__ src, u16* __restrict__ dst, int n) {
  int i = (blockIdx.x * blockDim.x + threadIdx.x) * 4;
  if (i >= n) return;
  float4 f = *(const float4*)(src + i);
  ushort4 o;
  o.x = f2bf(f.x); o.y = f2bf(f.y); o.z = f2bf(f.z); o.w = f2bf(f.w);
  *(ushort4*)(dst + i) = o;
}

// ---------------- fp32 -> bf16, 8 elems/thread (weights) ----------------
__global__ void cvt8_k(const float* __restrict__ src, u16* __restrict__ dst, int n8) {
  int i = blockIdx.x * blockDim.x + threadIdx.x;
  if (i >= n8) return;
  *(int4*)(dst + (size_t)i * 8) = pack8(src + (size_t)i * 8);
}

// ---------------- GEMM1: h = silu(x@Wg^T) * (x@Wu^T) * route_w ----------------
__global__ __launch_bounds__(256) void gemm1_k(
    const u16* __restrict__ hs16, const u16* __restrict__ gup16,
    const Meta* __restrict__ meta, const int* __restrict__ slot_token,
    const float* __restrict__ slot_w, u16* __restrict__ hbuf) {
  int tile = blockIdx.x;
  if (tile >= meta->n_tiles) return;
  int e = meta->tile_e[tile], mbase = meta->tile_m[tile], nrows = meta->tile_n[tile];
  int n0 = blockIdx.y * 64;                     // within IDIM

  __shared__ int4 As[512], Bg[512], Bu[512];    // 64x64 bf16 tiles, 16B-swizzled
  int tid = threadIdx.x;
  int lane = tid & 63, w = tid >> 6, wm = w >> 1, wn = w & 1;
  f32x4 accg[2][2] = {}; f32x4 accu[2][2] = {};
  const size_t wbase = (size_t)e * (2 * IDIM) * HDIM;

  for (int k0 = 0; k0 < HDIM; k0 += 64) {
    __syncthreads();
    #pragma unroll
    for (int c = tid; c < 512; c += 256) {      // stage A (gathered tokens, bf16)
      int row = c >> 3, slot = c & 7;
      int4 v = {0, 0, 0, 0};
      if (row < nrows) {
        int tok = slot_token[mbase + row];
        v = *(const int4*)(hs16 + (size_t)tok * HDIM + k0 + slot * 8);
      }
      As[(row << 3) | (slot ^ (row & 7))] = v;
    }
    #pragma unroll
    for (int c = tid; c < 512; c += 256) {      // stage Wg and Wu rows (bf16, no cvt)
      int row = c >> 3, slot = c & 7;
      const u16* pg = gup16 + wbase + (size_t)(n0 + row) * HDIM + k0 + slot * 8;
      int idx = (row << 3) | (slot ^ (row & 7));
      Bg[idx] = *(const int4*)pg;
      Bu[idx] = *(const int4*)(pg + (size_t)IDIM * HDIM);
    }
    __syncthreads();
    #pragma unroll
    for (int ks = 0; ks < 2; ++ks) {
      bf16x8 af[2], bgf[2], buf_[2];
      int slot = ks * 4 + (lane >> 4);
      #pragma unroll
      for (int i = 0; i < 2; ++i) {
        int row = wm * 32 + i * 16 + (lane & 15);
        af[i] = asbf(As[(row << 3) | (slot ^ (row & 7))]);
      }
      #pragma unroll
      for (int j = 0; j < 2; ++j) {
        int row = wn * 32 + j * 16 + (lane & 15);
        int idx = (row << 3) | (slot ^ (row & 7));
        bgf[j]  = asbf(Bg[idx]);
        buf_[j] = asbf(Bu[idx]);
      }
      #pragma unroll
      for (int i = 0; i < 2; ++i)
        #pragma unroll
        for (int j = 0; j < 2; ++j) {
          accg[i][j] = __builtin_amdgcn_mfma_f32_16x16x32_bf16(af[i], bgf[j],  accg[i][j], 0, 0, 0);
          accu[i][j] = __builtin_amdgcn_mfma_f32_16x16x32_bf16(af[i], buf_[j], accu[i][j], 0, 0, 0);
        }
    }
  }

  // epilogue: silu(g)*u * route_weight -> bf16 h
  int fq = lane >> 4, fr = lane & 15;
  #pragma unroll
  for (int i = 0; i < 2; ++i)
    #pragma unroll
    for (int r = 0; r < 4; ++r) {
      int row = wm * 32 + i * 16 + fq * 4 + r;
      if (row < nrows) {
        float wgt = slot_w[mbase + row];
        #pragma unroll
        for (int j = 0; j < 2; ++j) {
          float g = accg[i][j][r], u = accu[i][j][r];
          float s = g / (1.0f + __expf(-g));
          hbuf[(size_t)(mbase + row) * IDIM + n0 + wn * 32 + j * 16 + fr] = f2bf(s * u * wgt);
        }
      }
    }
}

// ---------------- GEMM2: out[tok] += h @ Wd^T ----------------
__global__ __launch_bounds__(256) void gemm2_k(
    const u16* __restrict__ hbuf, const u16* __restrict__ down16,
    const Meta* __restrict__ meta, const int* __restrict__ slot_token,
    float* __restrict__ out) {
  int tile = blockIdx.x;
  if (tile >= meta->n_tiles) return;
  int e = meta->tile_e[tile], mbase = meta->tile_m[tile], nrows = meta->tile_n[tile];
  int n0 = blockIdx.y * 64;                     // within HDIM

  __shared__ int4 As[512], Bs[512];
  int tid = threadIdx.x;
  int lane = tid & 63, w = tid >> 6, wm = w >> 1, wn = w & 1;
  f32x4 acc[2][2] = {};
  const size_t dbase = (size_t)e * HDIM * IDIM;

  for (int k0 = 0; k0 < IDIM; k0 += 64) {
    __syncthreads();
    #pragma unroll
    for (int c = tid; c < 512; c += 256) {      // stage h rows (contiguous slots, bf16)
      int row = c >> 3, slot = c & 7;
      As[(row << 3) | (slot ^ (row & 7))] =
          *(const int4*)(hbuf + (size_t)(mbase + row) * IDIM + k0 + slot * 8);
    }
    #pragma unroll
    for (int c = tid; c < 512; c += 256) {      // stage Wd rows (bf16, no cvt)
      int row = c >> 3, slot = c & 7;
      Bs[(row << 3) | (slot ^ (row & 7))] =
          *(const int4*)(down16 + dbase + (size_t)(n0 + row) * IDIM + k0 + slot * 8);
    }
    __syncthreads();
    #pragma unroll
    for (int ks = 0; ks < 2; ++ks) {
      bf16x8 af[2], bf[2];
      int slot = ks * 4 + (lane >> 4);
      #pragma unroll
      for (int i = 0; i < 2; ++i) {
        int row = wm * 32 + i * 16 + (lane & 15);
        af[i] = asbf(As[(row << 3) | (slot ^ (row & 7))]);
      }
      #pragma unroll
      for (int j = 0; j < 2; ++j) {
        int row = wn * 32 + j * 16 + (lane & 15);
        bf[j] = asbf(Bs[(row << 3) | (slot ^ (row & 7))]);
      }
      #pragma unroll
      for (int i = 0; i < 2; ++i)
        #pragma unroll
        for (int j = 0; j < 2; ++j)
          acc[i][j] = __builtin_amdgcn_mfma_f32_16x16x32_bf16(af[i], bf[j], acc[i][j], 0, 0, 0);
    }
  }

  int fq = lane >> 4, fr = lane & 15;
  #pragma unroll
  for (int i = 0; i < 2; ++i)
    #pragma unroll
    for (int r = 0; r < 4; ++r) {
      int row = wm * 32 + i * 16 + fq * 4 + r;
      if (row < nrows) {
        int tok = slot_token[mbase + row];
        #pragma unroll
        for (int j = 0; j < 2; ++j)
          atomicAdd(out + (size_t)tok * HDIM + n0 + wn * 32 + j * 16 + fr, acc[i][j][r]);
      }
    }
}

extern "C" void kernel_launch(void* const* d_in, const int* in_sizes, int n_in,
                              void* d_out, int out_size, void* d_ws, size_t ws_size,
                              hipStream_t stream) {
  const float* hs   = (const float*)d_in[0];
  const float* gup  = (const float*)d_in[1];
  const float* down = (const float*)d_in[2];
  const int*   topk = (const int*)d_in[3];
  const float* tw   = (const float*)d_in[4];
  float* out = (float*)d_out;

  // workspace layout (16B-aligned offsets)
  const size_t o_hs16   = 65536;
  const size_t o_hbuf   = o_hs16   + (size_t)T_TOK * HDIM * 2;           // 4,194,304
  const size_t o_gup16  = o_hbuf   + (size_t)SLOT_PAD * IDIM * 2;        // 6,488,064
  const size_t o_down16 = o_gup16  + (size_t)NEXP * 2 * IDIM * HDIM * 2; // 25,165,824
  const size_t needed   = o_down16 + (size_t)NEXP * HDIM * IDIM * 2;     // ~48.5 MB

  char* ws = (char*)d_ws;
  Meta*  meta       = (Meta*)ws;
  int*   slot_token = (int*)(ws + 4096);
  float* slot_w     = (float*)(ws + 4096 + SLOT_PAD * 4);
  u16*   hs16       = (u16*)(ws + o_hs16);
  u16*   hbuf       = (u16*)(ws + o_hbuf);
  u16*   gup16      = (u16*)(ws + o_gup16);
  u16*   down16     = (u16*)(ws + o_down16);

  if (ws_size < needed) return;   // refuse to corrupt memory; bench will show zeros

  hipMemsetAsync(d_out, 0, (size_t)out_size * sizeof(float), stream);
  route_k<<<1, 256, 0, stream>>>(topk, tw, meta, slot_token, slot_w);
  cvt_k<<<(T_TOK * HDIM / 4 + 255) / 256, 256, 0, stream>>>(hs, hs16, T_TOK * HDIM);
  {
    int n8g = NEXP * 2 * IDIM * HDIM / 8;   // 1,572,864
    int n8d = NEXP * HDIM * IDIM / 8;       //   786,432
    cvt8_k<<<(n8g + 255) / 256, 256, 0, stream>>>(gup,  gup16,  n8g);
    cvt8_k<<<(n8d + 255) / 256, 256, 0, stream>>>(down, down16, n8d);
  }
  gemm1_k<<<dim3(MAX_TILES, IDIM / 64), 256, 0, stream>>>(hs16, gup16, meta, slot_token, slot_w, hbuf);
  gemm2_k<<<dim3(MAX_TILES, HDIM / 64), 256, 0, stream>>>(hbuf, down16, meta, slot_token, out);
}

// Round 6
// 198.640 us; speedup vs baseline: 1.1017x; 1.1017x over previous
//
#include <hip/hip_runtime.h>
#include <hip/hip_bf16.h>

#define T_TOK   2048
#define NEXP    8
#define HDIM    1024
#define IDIM    768
#define TOPK    2
#define NASSIGN (T_TOK*TOPK)
#define MT      64
#define MAX_TILES 72
#define SLOT_PAD 4608   // MAX_TILES*64

typedef unsigned short u16;
typedef unsigned int   u32;

typedef __bf16 bf16x8 __attribute__((ext_vector_type(8)));
typedef float  f32x4  __attribute__((ext_vector_type(4)));

struct Meta {
  int n_tiles;
  int _pad[15];
  int tile_e[80];
  int tile_m[80];
  int tile_n[80];
};

__device__ __forceinline__ u16 f2bf(float f) {
  u32 x = __float_as_uint(f);
  return (u16)((x + 0x7fffu + ((x >> 16) & 1u)) >> 16);   // RNE, inputs finite
}

__device__ __forceinline__ int4 pack8(const float* __restrict__ p) {
  float4 a = *(const float4*)p;
  float4 b = *(const float4*)(p + 4);
  union { u16 u[8]; int4 v; } r;
  r.u[0] = f2bf(a.x); r.u[1] = f2bf(a.y); r.u[2] = f2bf(a.z); r.u[3] = f2bf(a.w);
  r.u[4] = f2bf(b.x); r.u[5] = f2bf(b.y); r.u[6] = f2bf(b.z); r.u[7] = f2bf(b.w);
  return r.v;
}

__device__ __forceinline__ bf16x8 asbf(int4 v) {
  return __builtin_bit_cast(bf16x8, v);
}

// async global->LDS, 16B per lane; lds ptr must be wave-uniform (lane scatters +16B each)
__device__ __forceinline__ void gll(const void* g, void* l) {
  __builtin_amdgcn_global_load_lds(
      (const __attribute__((address_space(1))) u32*)g,
      (__attribute__((address_space(3))) u32*)l, 16, 0, 0);
}

// ---------------- prep: route (block 0) + all fp32->bf16 + zero d_out ----------------
__global__ __launch_bounds__(256) void prep_k(
    const float* __restrict__ hs, const float* __restrict__ gup,
    const float* __restrict__ down, const int* __restrict__ topk,
    const float* __restrict__ tw,
    u16* __restrict__ hs16, u16* __restrict__ gup16, u16* __restrict__ down16,
    Meta* __restrict__ meta, int* __restrict__ slot_token, float* __restrict__ slot_w,
    float* __restrict__ out) {
  int tid = threadIdx.x;

  if (blockIdx.x == 0) {   // routing
    __shared__ int s_cnt[NEXP], s_off[NEXP], s_cur[NEXP];
    if (tid < NEXP) { s_cnt[tid] = 0; s_cur[tid] = 0; }
    __syncthreads();
    for (int i = tid; i < NASSIGN; i += 256)
      atomicAdd(&s_cnt[topk[i]], 1);
    __syncthreads();
    if (tid == 0) {
      int acc = 0, nt = 0;
      for (int e = 0; e < NEXP; ++e) {
        s_off[e] = acc;
        int c = s_cnt[e];
        for (int mb = 0; mb < c; mb += MT) {
          meta->tile_e[nt] = e;
          meta->tile_m[nt] = acc + mb;
          meta->tile_n[nt] = (c - mb) < MT ? (c - mb) : MT;
          ++nt;
        }
        acc += c;
      }
      meta->n_tiles = nt;
    }
    __syncthreads();
    for (int i = tid; i < NASSIGN; i += 256) {
      int e = topk[i];
      int p = s_off[e] + atomicAdd(&s_cur[e], 1);
      slot_token[p] = i / TOPK;
      slot_w[p]     = tw[i];
    }
    for (int i = NASSIGN + tid; i < SLOT_PAD; i += 256) {  // pad: token 0, weight 0
      slot_token[i] = 0;
      slot_w[i]     = 0.0f;
    }
  }

  // grid-stride conversion + output zeroing
  const size_t NG_GUP = (size_t)NEXP * 2 * IDIM * HDIM / 8;  // 1,572,864
  const size_t NG_DWN = (size_t)NEXP * HDIM * IDIM / 8;      //   786,432
  const size_t NG_HS  = (size_t)T_TOK * HDIM / 8;            //   262,144
  const size_t NG_OUT = (size_t)T_TOK * HDIM / 4;            //   524,288 int4-zeros
  const size_t TOT = NG_GUP + NG_DWN + NG_HS + NG_OUT;
  for (size_t g = (size_t)blockIdx.x * 256 + tid; g < TOT; g += (size_t)gridDim.x * 256) {
    if (g < NG_GUP) {
      *(int4*)(gup16 + g * 8) = pack8(gup + g * 8);
    } else if (g < NG_GUP + NG_DWN) {
      size_t i = g - NG_GUP;
      *(int4*)(down16 + i * 8) = pack8(down + i * 8);
    } else if (g < NG_GUP + NG_DWN + NG_HS) {
      size_t i = g - NG_GUP - NG_DWN;
      *(int4*)(hs16 + i * 8) = pack8(hs + i * 8);
    } else {
      size_t i = g - NG_GUP - NG_DWN - NG_HS;
      int4 z = {0, 0, 0, 0};
      *(int4*)(out + i * 4) = z;
    }
  }
}

// ---------------- GEMM1: h = silu(x@Wg^T) * (x@Wu^T) * route_w ----------------
// grid 864 = 72 tiles x 12 n-stripes, tile-major work + XCD swizzle.
__global__ __launch_bounds__(256, 3) void gemm1_k(
    const u16* __restrict__ hs16, const u16* __restrict__ gup16,
    const Meta* __restrict__ meta, const int* __restrict__ slot_token,
    const float* __restrict__ slot_w, u16* __restrict__ hbuf) {
  int bid = blockIdx.x;
  int wg = (bid & 7) * 108 + (bid >> 3);   // 864/8: chunk of 108 = ~9 tiles (1 expert) per XCD
  int tile = wg / 12, y = wg % 12;
  if (tile >= meta->n_tiles) return;
  int e = meta->tile_e[tile], mbase = meta->tile_m[tile], nrows = meta->tile_n[tile];
  int n0 = y * 64;

  __shared__ int4 lds[2][3][512];   // [dbuf][A|Bg|Bu], 64x64 bf16 each, src-side swizzle
  int tid = threadIdx.x, lane = tid & 63, w = tid >> 6, wm = w >> 1, wn = w & 1;
  f32x4 accg[2][2] = {}, accu[2][2] = {};

  const u16* gb = gup16 + (size_t)e * (2 * IDIM) * HDIM + (size_t)n0 * HDIM;
  const u16* ub = gb + (size_t)IDIM * HDIM;

  // fixed per-thread staging coords; source pre-swizzled (slot ^ row&7), LDS linear
  int c0 = tid, c1 = tid + 256;
  int r0 = c0 >> 3, s0 = (c0 & 7) ^ (r0 & 7);
  int r1 = c1 >> 3, s1 = (c1 & 7) ^ (r1 & 7);
  const u16* a0 = hs16 + (size_t)slot_token[mbase + r0] * HDIM + s0 * 8;
  const u16* a1 = hs16 + (size_t)slot_token[mbase + r1] * HDIM + s1 * 8;
  const u16* g0 = gb + (size_t)r0 * HDIM + s0 * 8;
  const u16* g1 = gb + (size_t)r1 * HDIM + s1 * 8;
  const u16* u0 = ub + (size_t)r0 * HDIM + s0 * 8;
  const u16* u1 = ub + (size_t)r1 * HDIM + s1 * 8;

  auto STAGE = [&](int b, int k0) {
    gll(a0 + k0, &lds[b][0][w * 64]);
    gll(a1 + k0, &lds[b][0][256 + w * 64]);
    gll(g0 + k0, &lds[b][1][w * 64]);
    gll(g1 + k0, &lds[b][1][256 + w * 64]);
    gll(u0 + k0, &lds[b][2][w * 64]);
    gll(u1 + k0, &lds[b][2][256 + w * 64]);
  };

  STAGE(0, 0);
  __syncthreads();
  int cur = 0;
  for (int k0 = 0; k0 < HDIM; k0 += 64) {
    if (k0 + 64 < HDIM) STAGE(cur ^ 1, k0 + 64);   // async loads in flight over MFMA
    #pragma unroll
    for (int ks = 0; ks < 2; ++ks) {
      bf16x8 af[2], bgf[2], buf_[2];
      int slot = ks * 4 + (lane >> 4);
      #pragma unroll
      for (int i = 0; i < 2; ++i) {
        int row = wm * 32 + i * 16 + (lane & 15);
        af[i] = asbf(lds[cur][0][(row << 3) | (slot ^ (row & 7))]);
      }
      #pragma unroll
      for (int j = 0; j < 2; ++j) {
        int row = wn * 32 + j * 16 + (lane & 15);
        int idx = (row << 3) | (slot ^ (row & 7));
        bgf[j]  = asbf(lds[cur][1][idx]);
        buf_[j] = asbf(lds[cur][2][idx]);
      }
      #pragma unroll
      for (int i = 0; i < 2; ++i)
        #pragma unroll
        for (int j = 0; j < 2; ++j) {
          accg[i][j] = __builtin_amdgcn_mfma_f32_16x16x32_bf16(af[i], bgf[j],  accg[i][j], 0, 0, 0);
          accu[i][j] = __builtin_amdgcn_mfma_f32_16x16x32_bf16(af[i], buf_[j], accu[i][j], 0, 0, 0);
        }
    }
    __syncthreads();   // drains vmcnt -> next buffer ready; guards overwrite
    cur ^= 1;
  }

  // epilogue: silu(g)*u*route_w -> bf16 h.
  // row < nrows guard is REQUIRED: rows beyond nrows in a partial tile are the
  // NEXT expert's slots (contiguous packing), owned by that expert's tile.
  int fq = lane >> 4, fr = lane & 15;
  #pragma unroll
  for (int i = 0; i < 2; ++i)
    #pragma unroll
    for (int r = 0; r < 4; ++r) {
      int row = wm * 32 + i * 16 + fq * 4 + r;
      if (row < nrows) {
        float wgt = slot_w[mbase + row];
        #pragma unroll
        for (int j = 0; j < 2; ++j) {
          float g = accg[i][j][r], u = accu[i][j][r];
          float s = g / (1.0f + __expf(-g));
          hbuf[(size_t)(mbase + row) * IDIM + n0 + wn * 32 + j * 16 + fr] = f2bf(s * u * wgt);
        }
      }
    }
}

// ---------------- GEMM2: out[tok] += h @ Wd^T ----------------
// grid 1152 = 72 tiles x 16 n-stripes, tile-major work + XCD swizzle.
__global__ __launch_bounds__(256, 3) void gemm2_k(
    const u16* __restrict__ hbuf, const u16* __restrict__ down16,
    const Meta* __restrict__ meta, const int* __restrict__ slot_token,
    float* __restrict__ out) {
  int bid = blockIdx.x;
  int wg = (bid & 7) * 144 + (bid >> 3);   // 1152/8
  int tile = wg / 16, y = wg % 16;
  if (tile >= meta->n_tiles) return;
  int e = meta->tile_e[tile], mbase = meta->tile_m[tile], nrows = meta->tile_n[tile];
  int n0 = y * 64;

  __shared__ int4 lds[2][2][512];
  int tid = threadIdx.x, lane = tid & 63, w = tid >> 6, wm = w >> 1, wn = w & 1;
  f32x4 acc[2][2] = {};
  const u16* db = down16 + (size_t)e * HDIM * IDIM + (size_t)n0 * IDIM;

  int c0 = tid, c1 = tid + 256;
  int r0 = c0 >> 3, s0 = (c0 & 7) ^ (r0 & 7);
  int r1 = c1 >> 3, s1 = (c1 & 7) ^ (r1 & 7);
  const u16* a0 = hbuf + (size_t)(mbase + r0) * IDIM + s0 * 8;
  const u16* a1 = hbuf + (size_t)(mbase + r1) * IDIM + s1 * 8;
  const u16* b0 = db + (size_t)r0 * IDIM + s0 * 8;
  const u16* b1 = db + (size_t)r1 * IDIM + s1 * 8;

  auto STAGE = [&](int b, int k0) {
    gll(a0 + k0, &lds[b][0][w * 64]);
    gll(a1 + k0, &lds[b][0][256 + w * 64]);
    gll(b0 + k0, &lds[b][1][w * 64]);
    gll(b1 + k0, &lds[b][1][256 + w * 64]);
  };

  STAGE(0, 0);
  __syncthreads();
  int cur = 0;
  for (int k0 = 0; k0 < IDIM; k0 += 64) {
    if (k0 + 64 < IDIM) STAGE(cur ^ 1, k0 + 64);
    #pragma unroll
    for (int ks = 0; ks < 2; ++ks) {
      bf16x8 af[2], bf[2];
      int slot = ks * 4 + (lane >> 4);
      #pragma unroll
      for (int i = 0; i < 2; ++i) {
        int row = wm * 32 + i * 16 + (lane & 15);
        af[i] = asbf(lds[cur][0][(row << 3) | (slot ^ (row & 7))]);
      }
      #pragma unroll
      for (int j = 0; j < 2; ++j) {
        int row = wn * 32 + j * 16 + (lane & 15);
        bf[j] = asbf(lds[cur][1][(row << 3) | (slot ^ (row & 7))]);
      }
      #pragma unroll
      for (int i = 0; i < 2; ++i)
        #pragma unroll
        for (int j = 0; j < 2; ++j)
          acc[i][j] = __builtin_amdgcn_mfma_f32_16x16x32_bf16(af[i], bf[j], acc[i][j], 0, 0, 0);
    }
    __syncthreads();
    cur ^= 1;
  }

  int fq = lane >> 4, fr = lane & 15;
  #pragma unroll
  for (int i = 0; i < 2; ++i)
    #pragma unroll
    for (int r = 0; r < 4; ++r) {
      int row = wm * 32 + i * 16 + fq * 4 + r;
      if (row < nrows) {
        int tok = slot_token[mbase + row];
        #pragma unroll
        for (int j = 0; j < 2; ++j)
          atomicAdd(out + (size_t)tok * HDIM + n0 + wn * 32 + j * 16 + fr, acc[i][j][r]);
      }
    }
}

extern "C" void kernel_launch(void* const* d_in, const int* in_sizes, int n_in,
                              void* d_out, int out_size, void* d_ws, size_t ws_size,
                              hipStream_t stream) {
  const float* hs   = (const float*)d_in[0];
  const float* gup  = (const float*)d_in[1];
  const float* down = (const float*)d_in[2];
  const int*   topk = (const int*)d_in[3];
  const float* tw   = (const float*)d_in[4];
  float* out = (float*)d_out;

  // workspace layout (16B-aligned)
  const size_t o_hs16   = 65536;
  const size_t o_hbuf   = o_hs16 + (size_t)T_TOK * HDIM * 2;                 //  4,259,840
  const size_t o_gup16  = o_hbuf + (size_t)SLOT_PAD * IDIM * 2;              // 11,337,728
  const size_t o_down16 = o_gup16 + (size_t)NEXP * 2 * IDIM * HDIM * 2;      // 36,503,552
  const size_t needed   = o_down16 + (size_t)NEXP * HDIM * IDIM * 2;         // 49,086,464

  char* ws = (char*)d_ws;
  Meta*  meta       = (Meta*)ws;
  int*   slot_token = (int*)(ws + 4096);
  float* slot_w     = (float*)(ws + 24576);
  u16*   hs16       = (u16*)(ws + o_hs16);
  u16*   hbuf       = (u16*)(ws + o_hbuf);
  u16*   gup16      = (u16*)(ws + o_gup16);
  u16*   down16     = (u16*)(ws + o_down16);

  if (ws_size < needed) return;

  prep_k<<<2048, 256, 0, stream>>>(hs, gup, down, topk, tw,
                                   hs16, gup16, down16, meta, slot_token, slot_w, out);
  gemm1_k<<<MAX_TILES * 12, 256, 0, stream>>>(hs16, gup16, meta, slot_token, slot_w, hbuf);
  gemm2_k<<<MAX_TILES * 16, 256, 0, stream>>>(hbuf, down16, meta, slot_token, out);
}

// Round 7
// 178.661 us; speedup vs baseline: 1.2249x; 1.1118x over previous
//
#include <hip/hip_runtime.h>
#include <hip/hip_bf16.h>

#define T_TOK   2048
#define NEXP    8
#define HDIM    1024
#define IDIM    768
#define TOPK    2
#define NASSIGN (T_TOK*TOPK)
#define MT      64
#define MAX_TILES 72
#define SLOT_PAD 4608   // MAX_TILES*64

typedef unsigned short u16;
typedef unsigned int   u32;

typedef __bf16 bf16x8 __attribute__((ext_vector_type(8)));
typedef float  f32x4  __attribute__((ext_vector_type(4)));

struct Meta {
  int n_tiles;
  int _pad[15];
  int tile_e[80];
  int tile_m[80];
  int tile_n[80];
};

__device__ __forceinline__ u16 f2bf(float f) {
  u32 x = __float_as_uint(f);
  return (u16)((x + 0x7fffu + ((x >> 16) & 1u)) >> 16);   // RNE, inputs finite
}

__device__ __forceinline__ int4 pack8(const float* __restrict__ p) {
  float4 a = *(const float4*)p;
  float4 b = *(const float4*)(p + 4);
  union { u16 u[8]; int4 v; } r;
  r.u[0] = f2bf(a.x); r.u[1] = f2bf(a.y); r.u[2] = f2bf(a.z); r.u[3] = f2bf(a.w);
  r.u[4] = f2bf(b.x); r.u[5] = f2bf(b.y); r.u[6] = f2bf(b.z); r.u[7] = f2bf(b.w);
  return r.v;
}

__device__ __forceinline__ bf16x8 asbf(int4 v) {
  return __builtin_bit_cast(bf16x8, v);
}

// async global->LDS, 16B per lane; lds ptr wave-uniform (lane scatters +16B each)
__device__ __forceinline__ void gll(const void* g, void* l) {
  __builtin_amdgcn_global_load_lds(
      (const __attribute__((address_space(1))) u32*)g,
      (__attribute__((address_space(3))) u32*)l, 16, 0, 0);
}

// ---------------- prep: route (block 0) + fp32->bf16 converts + zero d_out ----------------
// Per-segment loops, pair-unrolled: 4 independent float4 loads in flight per thread.
__global__ __launch_bounds__(256) void prep_k(
    const float* __restrict__ hs, const float* __restrict__ gup,
    const float* __restrict__ down, const int* __restrict__ topk,
    const float* __restrict__ tw,
    u16* __restrict__ hs16, u16* __restrict__ gup16, u16* __restrict__ down16,
    Meta* __restrict__ meta, int* __restrict__ slot_token, float* __restrict__ slot_w,
    float* __restrict__ out) {
  int tid = threadIdx.x;

  if (blockIdx.x == 0) {   // routing only; conversion handled by other 4095 blocks
    __shared__ int s_cnt[NEXP], s_off[NEXP], s_cur[NEXP];
    if (tid < NEXP) { s_cnt[tid] = 0; s_cur[tid] = 0; }
    __syncthreads();
    for (int i = tid; i < NASSIGN; i += 256)
      atomicAdd(&s_cnt[topk[i]], 1);
    __syncthreads();
    if (tid == 0) {
      int acc = 0, nt = 0;
      for (int e = 0; e < NEXP; ++e) {
        s_off[e] = acc;
        int c = s_cnt[e];
        for (int mb = 0; mb < c; mb += MT) {
          meta->tile_e[nt] = e;
          meta->tile_m[nt] = acc + mb;
          meta->tile_n[nt] = (c - mb) < MT ? (c - mb) : MT;
          ++nt;
        }
        acc += c;
      }
      meta->n_tiles = nt;
    }
    __syncthreads();
    for (int i = tid; i < NASSIGN; i += 256) {
      int e = topk[i];
      int p = s_off[e] + atomicAdd(&s_cur[e], 1);
      slot_token[p] = i / TOPK;
      slot_w[p]     = tw[i];
    }
    for (int i = NASSIGN + tid; i < SLOT_PAD; i += 256) {  // pad: token 0, weight 0
      slot_token[i] = 0;
      slot_w[i]     = 0.0f;
    }
    return;
  }

  const size_t NG_GUP = (size_t)NEXP * 2 * IDIM * HDIM / 8;  // 1,572,864 int4-groups
  const size_t NG_DWN = (size_t)NEXP * HDIM * IDIM / 8;      //   786,432
  const size_t NG_HS  = (size_t)T_TOK * HDIM / 8;            //   262,144
  const size_t NG_OUT = (size_t)T_TOK * HDIM / 4;            //   524,288 (int4 zeros)
  size_t gid    = ((size_t)(blockIdx.x - 1) * 256 + tid) * 2;
  size_t stride = (size_t)(gridDim.x - 1) * 256 * 2;

  for (size_t g = gid; g < NG_GUP; g += stride) {
    *(int4*)(gup16 + g * 8)     = pack8(gup + g * 8);
    *(int4*)(gup16 + g * 8 + 8) = pack8(gup + g * 8 + 8);
  }
  for (size_t g = gid; g < NG_DWN; g += stride) {
    *(int4*)(down16 + g * 8)     = pack8(down + g * 8);
    *(int4*)(down16 + g * 8 + 8) = pack8(down + g * 8 + 8);
  }
  for (size_t g = gid; g < NG_HS; g += stride) {
    *(int4*)(hs16 + g * 8)     = pack8(hs + g * 8);
    *(int4*)(hs16 + g * 8 + 8) = pack8(hs + g * 8 + 8);
  }
  int4 z = {0, 0, 0, 0};
  for (size_t g = gid; g < NG_OUT; g += stride) {
    *(int4*)(out + g * 4)     = z;
    *(int4*)(out + g * 4 + 4) = z;
  }
}

// ---------------- GEMM1: h = silu(x@Wg^T) * (x@Wu^T) * route_w ----------------
// grid 864 = 72 tiles x 12 n-stripes, tile-major + XCD chunk swizzle.
// 3-slot LDS rotation, counted vmcnt (never 0 mid-loop), raw barriers.
__global__ __launch_bounds__(256, 2) void gemm1_k(
    const u16* __restrict__ hs16, const u16* __restrict__ gup16,
    const Meta* __restrict__ meta, const int* __restrict__ slot_token,
    const float* __restrict__ slot_w, u16* __restrict__ hbuf) {
  int bid = blockIdx.x;
  int wg = (bid & 7) * 108 + (bid >> 3);   // 864/8 chunk: ~1 expert per XCD
  int tile = wg / 12, y = wg % 12;
  if (tile >= meta->n_tiles) return;
  int e = meta->tile_e[tile], mbase = meta->tile_m[tile], nrows = meta->tile_n[tile];
  int n0 = y * 64;

  __shared__ int4 lds[3][3][512];   // [slot][A|Bg|Bu], 64x64 bf16 each; 72 KB
  int tid = threadIdx.x, lane = tid & 63, w = tid >> 6, wm = w >> 1, wn = w & 1;
  f32x4 accg[2][2] = {}, accu[2][2] = {};

  const u16* gb = gup16 + (size_t)e * (2 * IDIM) * HDIM + (size_t)n0 * HDIM;
  const u16* ub = gb + (size_t)IDIM * HDIM;

  // per-thread staging coords; source pre-swizzled (slot ^ row&7), LDS linear (rule 21)
  int c0 = tid, c1 = tid + 256;
  int r0 = c0 >> 3, s0 = (c0 & 7) ^ (r0 & 7);
  int r1 = c1 >> 3, s1 = (c1 & 7) ^ (r1 & 7);
  const u16* a0 = hs16 + (size_t)slot_token[mbase + r0] * HDIM + s0 * 8;
  const u16* a1 = hs16 + (size_t)slot_token[mbase + r1] * HDIM + s1 * 8;
  const u16* g0 = gb + (size_t)r0 * HDIM + s0 * 8;
  const u16* g1 = gb + (size_t)r1 * HDIM + s1 * 8;
  const u16* u0 = ub + (size_t)r0 * HDIM + s0 * 8;
  const u16* u1 = ub + (size_t)r1 * HDIM + s1 * 8;

  auto STAGE = [&](int b, int k0) {   // 6 gll per wave
    gll(a0 + k0, &lds[b][0][w * 64]);
    gll(a1 + k0, &lds[b][0][256 + w * 64]);
    gll(g0 + k0, &lds[b][1][w * 64]);
    gll(g1 + k0, &lds[b][1][256 + w * 64]);
    gll(u0 + k0, &lds[b][2][w * 64]);
    gll(u1 + k0, &lds[b][2][256 + w * 64]);
  };

  STAGE(0, 0);
  STAGE(1, 64);
  #pragma unroll
  for (int kt = 0; kt < 16; ++kt) {          // NT = HDIM/64 = 16
    __builtin_amdgcn_s_barrier();            // iter kt-1 readers done with slot (kt+2)%3
    if (kt + 2 < 16) STAGE((kt + 2) % 3, (kt + 2) * 64);
    // wait for slot kt's 6 loads (issued 2 iters ago); leave newer groups in flight
    if (kt < 14)       asm volatile("s_waitcnt vmcnt(12)" ::: "memory");
    else if (kt == 14) asm volatile("s_waitcnt vmcnt(6)" ::: "memory");
    else               asm volatile("s_waitcnt vmcnt(0)" ::: "memory");
    __builtin_amdgcn_sched_barrier(0);
    const int cur = kt % 3;
    #pragma unroll
    for (int ks = 0; ks < 2; ++ks) {
      bf16x8 af[2], bgf[2], buf_[2];
      int slot = ks * 4 + (lane >> 4);
      #pragma unroll
      for (int i = 0; i < 2; ++i) {
        int row = wm * 32 + i * 16 + (lane & 15);
        af[i] = asbf(lds[cur][0][(row << 3) | (slot ^ (row & 7))]);
      }
      #pragma unroll
      for (int j = 0; j < 2; ++j) {
        int row = wn * 32 + j * 16 + (lane & 15);
        int idx = (row << 3) | (slot ^ (row & 7));
        bgf[j]  = asbf(lds[cur][1][idx]);
        buf_[j] = asbf(lds[cur][2][idx]);
      }
      #pragma unroll
      for (int i = 0; i < 2; ++i)
        #pragma unroll
        for (int j = 0; j < 2; ++j) {
          accg[i][j] = __builtin_amdgcn_mfma_f32_16x16x32_bf16(af[i], bgf[j],  accg[i][j], 0, 0, 0);
          accu[i][j] = __builtin_amdgcn_mfma_f32_16x16x32_bf16(af[i], buf_[j], accu[i][j], 0, 0, 0);
        }
    }
  }

  // epilogue: silu(g)*u*route_w -> bf16 h.
  // row < nrows guard REQUIRED: rows past nrows belong to the NEXT expert's tile.
  int fq = lane >> 4, fr = lane & 15;
  #pragma unroll
  for (int i = 0; i < 2; ++i)
    #pragma unroll
    for (int r = 0; r < 4; ++r) {
      int row = wm * 32 + i * 16 + fq * 4 + r;
      if (row < nrows) {
        float wgt = slot_w[mbase + row];
        #pragma unroll
        for (int j = 0; j < 2; ++j) {
          float g = accg[i][j][r], u = accu[i][j][r];
          float s = g / (1.0f + __expf(-g));
          hbuf[(size_t)(mbase + row) * IDIM + n0 + wn * 32 + j * 16 + fr] = f2bf(s * u * wgt);
        }
      }
    }
}

// ---------------- GEMM2: out[tok] += h @ Wd^T ----------------
// grid 1152 = 72 tiles x 16 n-stripes; same 3-slot counted-vmcnt pipeline.
__global__ __launch_bounds__(256, 3) void gemm2_k(
    const u16* __restrict__ hbuf, const u16* __restrict__ down16,
    const Meta* __restrict__ meta, const int* __restrict__ slot_token,
    float* __restrict__ out) {
  int bid = blockIdx.x;
  int wg = (bid & 7) * 144 + (bid >> 3);   // 1152/8
  int tile = wg / 16, y = wg % 16;
  if (tile >= meta->n_tiles) return;
  int e = meta->tile_e[tile], mbase = meta->tile_m[tile], nrows = meta->tile_n[tile];
  int n0 = y * 64;

  __shared__ int4 lds[3][2][512];   // 48 KB
  int tid = threadIdx.x, lane = tid & 63, w = tid >> 6, wm = w >> 1, wn = w & 1;
  f32x4 acc[2][2] = {};
  const u16* db = down16 + (size_t)e * HDIM * IDIM + (size_t)n0 * IDIM;

  int c0 = tid, c1 = tid + 256;
  int r0 = c0 >> 3, s0 = (c0 & 7) ^ (r0 & 7);
  int r1 = c1 >> 3, s1 = (c1 & 7) ^ (r1 & 7);
  const u16* a0 = hbuf + (size_t)(mbase + r0) * IDIM + s0 * 8;
  const u16* a1 = hbuf + (size_t)(mbase + r1) * IDIM + s1 * 8;
  const u16* b0 = db + (size_t)r0 * IDIM + s0 * 8;
  const u16* b1 = db + (size_t)r1 * IDIM + s1 * 8;

  auto STAGE = [&](int b, int k0) {   // 4 gll per wave
    gll(a0 + k0, &lds[b][0][w * 64]);
    gll(a1 + k0, &lds[b][0][256 + w * 64]);
    gll(b0 + k0, &lds[b][1][w * 64]);
    gll(b1 + k0, &lds[b][1][256 + w * 64]);
  };

  STAGE(0, 0);
  STAGE(1, 64);
  #pragma unroll
  for (int kt = 0; kt < 12; ++kt) {          // NT = IDIM/64 = 12
    __builtin_amdgcn_s_barrier();
    if (kt + 2 < 12) STAGE((kt + 2) % 3, (kt + 2) * 64);
    if (kt < 10)       asm volatile("s_waitcnt vmcnt(8)" ::: "memory");
    else if (kt == 10) asm volatile("s_waitcnt vmcnt(4)" ::: "memory");
    else               asm volatile("s_waitcnt vmcnt(0)" ::: "memory");
    __builtin_amdgcn_sched_barrier(0);
    const int cur = kt % 3;
    #pragma unroll
    for (int ks = 0; ks < 2; ++ks) {
      bf16x8 af[2], bf[2];
      int slot = ks * 4 + (lane >> 4);
      #pragma unroll
      for (int i = 0; i < 2; ++i) {
        int row = wm * 32 + i * 16 + (lane & 15);
        af[i] = asbf(lds[cur][0][(row << 3) | (slot ^ (row & 7))]);
      }
      #pragma unroll
      for (int j = 0; j < 2; ++j) {
        int row = wn * 32 + j * 16 + (lane & 15);
        bf[j] = asbf(lds[cur][1][(row << 3) | (slot ^ (row & 7))]);
      }
      #pragma unroll
      for (int i = 0; i < 2; ++i)
        #pragma unroll
        for (int j = 0; j < 2; ++j)
          acc[i][j] = __builtin_amdgcn_mfma_f32_16x16x32_bf16(af[i], bf[j], acc[i][j], 0, 0, 0);
    }
  }

  int fq = lane >> 4, fr = lane & 15;
  #pragma unroll
  for (int i = 0; i < 2; ++i)
    #pragma unroll
    for (int r = 0; r < 4; ++r) {
      int row = wm * 32 + i * 16 + fq * 4 + r;
      if (row < nrows) {
        int tok = slot_token[mbase + row];
        #pragma unroll
        for (int j = 0; j < 2; ++j)
          atomicAdd(out + (size_t)tok * HDIM + n0 + wn * 32 + j * 16 + fr, acc[i][j][r]);
      }
    }
}

extern "C" void kernel_launch(void* const* d_in, const int* in_sizes, int n_in,
                              void* d_out, int out_size, void* d_ws, size_t ws_size,
                              hipStream_t stream) {
  const float* hs   = (const float*)d_in[0];
  const float* gup  = (const float*)d_in[1];
  const float* down = (const float*)d_in[2];
  const int*   topk = (const int*)d_in[3];
  const float* tw   = (const float*)d_in[4];
  float* out = (float*)d_out;

  // workspace layout (16B-aligned)
  const size_t o_hs16   = 65536;
  const size_t o_hbuf   = o_hs16 + (size_t)T_TOK * HDIM * 2;
  const size_t o_gup16  = o_hbuf + (size_t)SLOT_PAD * IDIM * 2;
  const size_t o_down16 = o_gup16 + (size_t)NEXP * 2 * IDIM * HDIM * 2;
  const size_t needed   = o_down16 + (size_t)NEXP * HDIM * IDIM * 2;   // ~49 MB

  char* ws = (char*)d_ws;
  Meta*  meta       = (Meta*)ws;
  int*   slot_token = (int*)(ws + 4096);
  float* slot_w     = (float*)(ws + 24576);
  u16*   hs16       = (u16*)(ws + o_hs16);
  u16*   hbuf       = (u16*)(ws + o_hbuf);
  u16*   gup16      = (u16*)(ws + o_gup16);
  u16*   down16     = (u16*)(ws + o_down16);

  if (ws_size < needed) return;

  prep_k<<<4096, 256, 0, stream>>>(hs, gup, down, topk, tw,
                                   hs16, gup16, down16, meta, slot_token, slot_w, out);
  gemm1_k<<<MAX_TILES * 12, 256, 0, stream>>>(hs16, gup16, meta, slot_token, slot_w, hbuf);
  gemm2_k<<<MAX_TILES * 16, 256, 0, stream>>>(hbuf, down16, meta, slot_token, out);
}

// Round 8
// 177.728 us; speedup vs baseline: 1.2314x; 1.0053x over previous
//
#include <hip/hip_runtime.h>
#include <hip/hip_bf16.h>

#define T_TOK   2048
#define NEXP    8
#define HDIM    1024
#define IDIM    768
#define TOPK    2
#define NASSIGN (T_TOK*TOPK)
#define MT      128
#define MAX_TILES 40
#define SLOT_PAD 5120   // MAX_TILES*128

typedef unsigned short u16;
typedef unsigned int   u32;

typedef __bf16 bf16x8 __attribute__((ext_vector_type(8)));
typedef float  f32x4  __attribute__((ext_vector_type(4)));

struct Meta {
  int n_tiles;
  int _pad[15];
  int tile_e[80];
  int tile_m[80];
  int tile_n[80];
};

__device__ __forceinline__ u16 f2bf(float f) {
  u32 x = __float_as_uint(f);
  return (u16)((x + 0x7fffu + ((x >> 16) & 1u)) >> 16);   // RNE, inputs finite
}

__device__ __forceinline__ int4 pack8(const float* __restrict__ p) {
  float4 a = *(const float4*)p;
  float4 b = *(const float4*)(p + 4);
  union { u16 u[8]; int4 v; } r;
  r.u[0] = f2bf(a.x); r.u[1] = f2bf(a.y); r.u[2] = f2bf(a.z); r.u[3] = f2bf(a.w);
  r.u[4] = f2bf(b.x); r.u[5] = f2bf(b.y); r.u[6] = f2bf(b.z); r.u[7] = f2bf(b.w);
  return r.v;
}

__device__ __forceinline__ bf16x8 asbf(int4 v) {
  return __builtin_bit_cast(bf16x8, v);
}

// async global->LDS, 16B per lane; lds ptr wave-uniform (lane scatters +16B each)
__device__ __forceinline__ void gll(const void* g, void* l) {
  __builtin_amdgcn_global_load_lds(
      (const __attribute__((address_space(1))) u32*)g,
      (__attribute__((address_space(3))) u32*)l, 16, 0, 0);
}

// ---------------- prep: route (block 0) + fp32->bf16 converts + zero d_out ----------------
// 512 conversion blocks; every thread runs DEEP, exactly-divisible, per-instruction-
// coalesced loops (segment_size % 131072 == 0) -> long-lived waves, no dispatch churn.
__global__ __launch_bounds__(256) void prep_k(
    const float* __restrict__ hs, const float* __restrict__ gup,
    const float* __restrict__ down, const int* __restrict__ topk,
    const float* __restrict__ tw,
    u16* __restrict__ hs16, u16* __restrict__ gup16, u16* __restrict__ down16,
    Meta* __restrict__ meta, int* __restrict__ slot_token, float* __restrict__ slot_w,
    float* __restrict__ out) {
  int tid = threadIdx.x;

  if (blockIdx.x == 0) {   // routing only
    __shared__ int s_cnt[NEXP], s_off[NEXP], s_cur[NEXP];
    if (tid < NEXP) { s_cnt[tid] = 0; s_cur[tid] = 0; }
    __syncthreads();
    for (int i = tid; i < NASSIGN; i += 256)
      atomicAdd(&s_cnt[topk[i]], 1);
    __syncthreads();
    if (tid == 0) {
      int acc = 0, nt = 0;
      for (int e = 0; e < NEXP; ++e) {
        s_off[e] = acc;
        int c = s_cnt[e];
        for (int mb = 0; mb < c; mb += MT) {
          meta->tile_e[nt] = e;
          meta->tile_m[nt] = acc + mb;
          meta->tile_n[nt] = (c - mb) < MT ? (c - mb) : MT;
          ++nt;
        }
        acc += c;
      }
      meta->n_tiles = nt;
    }
    __syncthreads();
    for (int i = tid; i < NASSIGN; i += 256) {
      int e = topk[i];
      int p = s_off[e] + atomicAdd(&s_cur[e], 1);
      slot_token[p] = i / TOPK;
      slot_w[p]     = tw[i];
    }
    for (int i = NASSIGN + tid; i < SLOT_PAD; i += 256) {  // pad: token 0, weight 0
      slot_token[i] = 0;
      slot_w[i]     = 0.0f;
    }
    return;
  }

  const size_t NTH = 512 * 256;                       // 131,072 conversion threads
  size_t t = ((size_t)blockIdx.x - 1) * 256 + tid;

  // gup: 1,572,864 groups = 12 * NTH exactly
  #pragma unroll
  for (int k = 0; k < 12; ++k) {
    size_t i = t + (size_t)k * NTH;
    *(int4*)(gup16 + i * 8) = pack8(gup + i * 8);
  }
  // down: 786,432 = 6 * NTH
  #pragma unroll
  for (int k = 0; k < 6; ++k) {
    size_t i = t + (size_t)k * NTH;
    *(int4*)(down16 + i * 8) = pack8(down + i * 8);
  }
  // hs: 262,144 = 2 * NTH
  #pragma unroll
  for (int k = 0; k < 2; ++k) {
    size_t i = t + (size_t)k * NTH;
    *(int4*)(hs16 + i * 8) = pack8(hs + i * 8);
  }
  // out zero: 524,288 int4 = 4 * NTH
  int4 z = {0, 0, 0, 0};
  #pragma unroll
  for (int k = 0; k < 4; ++k) {
    size_t i = t + (size_t)k * NTH;
    *(int4*)(out + i * 4) = z;
  }
}

// ---------------- GEMM1: h = silu(x@Wg^T) * (x@Wu^T) * route_w ----------------
// 128x128 tiles, 512 threads (2x4 waves), 3-slot LDS (144 KB), counted vmcnt.
// grid 240 = 40 tiles x 6 n-stripes, XCD-chunked.
__global__ __launch_bounds__(512, 2) void gemm1_k(
    const u16* __restrict__ hs16, const u16* __restrict__ gup16,
    const Meta* __restrict__ meta, const int* __restrict__ slot_token,
    const float* __restrict__ slot_w, u16* __restrict__ hbuf) {
  int bid = blockIdx.x;
  int wg = (bid & 7) * 30 + (bid >> 3);   // 240/8 = 30 per XCD: ~5 tiles ~ 1 expert
  int tile = wg / 6, y = wg % 6;
  if (tile >= meta->n_tiles) return;
  int e = meta->tile_e[tile], mbase = meta->tile_m[tile], nrows = meta->tile_n[tile];
  int n0 = y * 128;

  __shared__ int4 lds[3][3][1024];   // [slot][A|Bg|Bu], 128x64 bf16 each; 144 KB
  int tid = threadIdx.x, lane = tid & 63, w = tid >> 6;
  int wm = w >> 2, wn = w & 3;       // wave grid 2(M) x 4(N); wave tile 64x32
  f32x4 accg[4][2] = {}, accu[4][2] = {};

  const u16* gb = gup16 + (size_t)e * (2 * IDIM) * HDIM + (size_t)n0 * HDIM;
  const u16* ub = gb + (size_t)IDIM * HDIM;

  // per-thread staging coords; source pre-swizzled (slot ^ row&7), LDS linear (rule 21)
  int c0 = tid, c1 = tid + 512;
  int r0 = c0 >> 3, s0 = (c0 & 7) ^ (r0 & 7);
  int r1 = c1 >> 3, s1 = (c1 & 7) ^ (r1 & 7);
  const u16* a0 = hs16 + (size_t)slot_token[mbase + r0] * HDIM + s0 * 8;
  const u16* a1 = hs16 + (size_t)slot_token[mbase + r1] * HDIM + s1 * 8;
  const u16* g0 = gb + (size_t)r0 * HDIM + s0 * 8;
  const u16* g1 = gb + (size_t)r1 * HDIM + s1 * 8;
  const u16* u0 = ub + (size_t)r0 * HDIM + s0 * 8;
  const u16* u1 = ub + (size_t)r1 * HDIM + s1 * 8;

  auto STAGE = [&](int b, int k0) {   // 6 gll per wave
    gll(a0 + k0, &lds[b][0][w * 64]);
    gll(a1 + k0, &lds[b][0][512 + w * 64]);
    gll(g0 + k0, &lds[b][1][w * 64]);
    gll(g1 + k0, &lds[b][1][512 + w * 64]);
    gll(u0 + k0, &lds[b][2][w * 64]);
    gll(u1 + k0, &lds[b][2][512 + w * 64]);
  };

  STAGE(0, 0);
  STAGE(1, 64);
  #pragma unroll
  for (int kt = 0; kt < 16; ++kt) {          // NT = HDIM/64 = 16
    __builtin_amdgcn_s_barrier();            // iter kt-1 readers done with slot (kt+2)%3
    if (kt + 2 < 16) STAGE((kt + 2) % 3, (kt + 2) * 64);
    if (kt < 14)       asm volatile("s_waitcnt vmcnt(12)" ::: "memory");
    else if (kt == 14) asm volatile("s_waitcnt vmcnt(6)" ::: "memory");
    else               asm volatile("s_waitcnt vmcnt(0)" ::: "memory");
    __builtin_amdgcn_sched_barrier(0);
    const int cur = kt % 3;
    #pragma unroll
    for (int ks = 0; ks < 2; ++ks) {
      bf16x8 af[4], bgf[2], buf_[2];
      int slot = ks * 4 + (lane >> 4);
      #pragma unroll
      for (int i = 0; i < 4; ++i) {
        int row = wm * 64 + i * 16 + (lane & 15);
        af[i] = asbf(lds[cur][0][(row << 3) | (slot ^ (row & 7))]);
      }
      #pragma unroll
      for (int j = 0; j < 2; ++j) {
        int row = wn * 32 + j * 16 + (lane & 15);
        int idx = (row << 3) | (slot ^ (row & 7));
        bgf[j]  = asbf(lds[cur][1][idx]);
        buf_[j] = asbf(lds[cur][2][idx]);
      }
      #pragma unroll
      for (int i = 0; i < 4; ++i)
        #pragma unroll
        for (int j = 0; j < 2; ++j) {
          accg[i][j] = __builtin_amdgcn_mfma_f32_16x16x32_bf16(af[i], bgf[j],  accg[i][j], 0, 0, 0);
          accu[i][j] = __builtin_amdgcn_mfma_f32_16x16x32_bf16(af[i], buf_[j], accu[i][j], 0, 0, 0);
        }
    }
  }

  // epilogue: silu(g)*u*route_w -> bf16 h.
  // row < nrows guard REQUIRED: rows past nrows belong to the NEXT expert's tile.
  int fq = lane >> 4, fr = lane & 15;
  #pragma unroll
  for (int i = 0; i < 4; ++i)
    #pragma unroll
    for (int r = 0; r < 4; ++r) {
      int row = wm * 64 + i * 16 + fq * 4 + r;
      if (row < nrows) {
        float wgt = slot_w[mbase + row];
        #pragma unroll
        for (int j = 0; j < 2; ++j) {
          float g = accg[i][j][r], u = accu[i][j][r];
          float s = g / (1.0f + __expf(-g));
          hbuf[(size_t)(mbase + row) * IDIM + n0 + wn * 32 + j * 16 + fr] = f2bf(s * u * wgt);
        }
      }
    }
}

// ---------------- GEMM2: out[tok] += h @ Wd^T ----------------
// 128x128 tiles, 512 threads, 2-slot LDS (64 KB -> 2 blocks/CU), counted vmcnt.
// grid 320 = 40 tiles x 8 n-stripes, XCD-chunked.
__global__ __launch_bounds__(512, 4) void gemm2_k(
    const u16* __restrict__ hbuf, const u16* __restrict__ down16,
    const Meta* __restrict__ meta, const int* __restrict__ slot_token,
    float* __restrict__ out) {
  int bid = blockIdx.x;
  int wg = (bid & 7) * 40 + (bid >> 3);   // 320/8 = 40 per XCD
  int tile = wg / 8, y = wg % 8;
  if (tile >= meta->n_tiles) return;
  int e = meta->tile_e[tile], mbase = meta->tile_m[tile], nrows = meta->tile_n[tile];
  int n0 = y * 128;

  __shared__ int4 lds[2][2][1024];   // [slot][A|B], 128x64 bf16 each; 64 KB
  int tid = threadIdx.x, lane = tid & 63, w = tid >> 6;
  int wm = w >> 2, wn = w & 3;
  f32x4 acc[4][2] = {};
  const u16* db = down16 + (size_t)e * HDIM * IDIM + (size_t)n0 * IDIM;

  int c0 = tid, c1 = tid + 512;
  int r0 = c0 >> 3, s0 = (c0 & 7) ^ (r0 & 7);
  int r1 = c1 >> 3, s1 = (c1 & 7) ^ (r1 & 7);
  const u16* a0 = hbuf + (size_t)(mbase + r0) * IDIM + s0 * 8;
  const u16* a1 = hbuf + (size_t)(mbase + r1) * IDIM + s1 * 8;
  const u16* b0 = db + (size_t)r0 * IDIM + s0 * 8;
  const u16* b1 = db + (size_t)r1 * IDIM + s1 * 8;

  auto STAGE = [&](int b, int k0) {   // 4 gll per wave
    gll(a0 + k0, &lds[b][0][w * 64]);
    gll(a1 + k0, &lds[b][0][512 + w * 64]);
    gll(b0 + k0, &lds[b][1][w * 64]);
    gll(b1 + k0, &lds[b][1][512 + w * 64]);
  };

  STAGE(0, 0);
  #pragma unroll
  for (int kt = 0; kt < 12; ++kt) {          // NT = IDIM/64 = 12
    __builtin_amdgcn_s_barrier();            // iter kt-1 readers done with slot (kt+1)&1
    if (kt + 1 < 12) STAGE((kt + 1) & 1, (kt + 1) * 64);
    if (kt < 11) asm volatile("s_waitcnt vmcnt(4)" ::: "memory");
    else         asm volatile("s_waitcnt vmcnt(0)" ::: "memory");
    __builtin_amdgcn_sched_barrier(0);
    const int cur = kt & 1;
    #pragma unroll
    for (int ks = 0; ks < 2; ++ks) {
      bf16x8 af[4], bf[2];
      int slot = ks * 4 + (lane >> 4);
      #pragma unroll
      for (int i = 0; i < 4; ++i) {
        int row = wm * 64 + i * 16 + (lane & 15);
        af[i] = asbf(lds[cur][0][(row << 3) | (slot ^ (row & 7))]);
      }
      #pragma unroll
      for (int j = 0; j < 2; ++j) {
        int row = wn * 32 + j * 16 + (lane & 15);
        bf[j] = asbf(lds[cur][1][(row << 3) | (slot ^ (row & 7))]);
      }
      #pragma unroll
      for (int i = 0; i < 4; ++i)
        #pragma unroll
        for (int j = 0; j < 2; ++j)
          acc[i][j] = __builtin_amdgcn_mfma_f32_16x16x32_bf16(af[i], bf[j], acc[i][j], 0, 0, 0);
    }
  }

  int fq = lane >> 4, fr = lane & 15;
  #pragma unroll
  for (int i = 0; i < 4; ++i)
    #pragma unroll
    for (int r = 0; r < 4; ++r) {
      int row = wm * 64 + i * 16 + fq * 4 + r;
      if (row < nrows) {
        int tok = slot_token[mbase + row];
        #pragma unroll
        for (int j = 0; j < 2; ++j)
          atomicAdd(out + (size_t)tok * HDIM + n0 + wn * 32 + j * 16 + fr, acc[i][j][r]);
      }
    }
}

extern "C" void kernel_launch(void* const* d_in, const int* in_sizes, int n_in,
                              void* d_out, int out_size, void* d_ws, size_t ws_size,
                              hipStream_t stream) {
  const float* hs   = (const float*)d_in[0];
  const float* gup  = (const float*)d_in[1];
  const float* down = (const float*)d_in[2];
  const int*   topk = (const int*)d_in[3];
  const float* tw   = (const float*)d_in[4];
  float* out = (float*)d_out;

  // workspace layout (16B-aligned)
  const size_t o_hs16   = 65536;
  const size_t o_hbuf   = o_hs16 + (size_t)T_TOK * HDIM * 2;               //  4,259,840
  const size_t o_gup16  = o_hbuf + (size_t)SLOT_PAD * IDIM * 2;            // 12,124,160
  const size_t o_down16 = o_gup16 + (size_t)NEXP * 2 * IDIM * HDIM * 2;    // 37,289,984
  const size_t needed   = o_down16 + (size_t)NEXP * HDIM * IDIM * 2;       // 49,872,896

  char* ws = (char*)d_ws;
  Meta*  meta       = (Meta*)ws;
  int*   slot_token = (int*)(ws + 4096);     // 5120*4 -> ends 24,576
  float* slot_w     = (float*)(ws + 24576);  // 5120*4 -> ends 45,056
  u16*   hs16       = (u16*)(ws + o_hs16);
  u16*   hbuf       = (u16*)(ws + o_hbuf);
  u16*   gup16      = (u16*)(ws + o_gup16);
  u16*   down16     = (u16*)(ws + o_down16);

  if (ws_size < needed) return;

  prep_k<<<513, 256, 0, stream>>>(hs, gup, down, topk, tw,
                                  hs16, gup16, down16, meta, slot_token, slot_w, out);
  gemm1_k<<<MAX_TILES * 6, 512, 0, stream>>>(hs16, gup16, meta, slot_token, slot_w, hbuf);
  gemm2_k<<<MAX_TILES * 8, 512, 0, stream>>>(hbuf, down16, meta, slot_token, out);
}